// Round 5
// baseline (4137.537 us; speedup 1.0000x reference)
//
#include <hip/hip_runtime.h>

// Spatially varying anisotropic 2D elastic wave sim, 384x384, 192 steps.
// Round 4: SINGLE persistent kernel, point-to-point neighbor flag sync.
//  - 256 blocks (8x32), each owns a 12x48 tile, 192 threads, 3 pts/thread
//  - NO time-tile redundancy (1x compute), NO per-step kernel launches
//  - state: ping-pong cur buffers in global (L2/LLC resident); old + coeffs
//    live in REGISTERS for all 192 steps (old is only ever read at center)
//  - sync: per-block step counter, agent-scope release store; 8 poller lanes
//    acquire-poll the 8 neighbors' counters (>= i-1 covers data+anti deps)
//  - deadlock-safe: 64KB dummy LDS -> <=2 blocks/CU -> capacity 512 >= 256
//    blocks => all co-resident; bounded spin avoids infinite hang

#define NXg 384
#define NYg 384
#define NPT (NXg * NYg)
#define NFRAMES 48
#define NSTEPS 192

#define TR 12          // tile rows
#define TC 48          // tile cols
#define GBX 8          // blocks along cols
#define GBY 32         // blocks along rows
#define NTHR 192       // 12 row-groups x 16 col-groups, 3 pts/thread
#define FLAG_STRIDE 32 // ints; 128B apart to avoid cacheline contention

#define H_   1e-4
#define DT_  5e-9
#define RHO_ 1610.0

#define B11_LO 5e10f
#define B11_HI 2.5e11f
#define B22_LO 5e9f
#define B22_HI 5e10f
#define B12_LO 5e9f
#define B12_HI 5e10f
#define B16_LO 0.0f
#define B16_HI 6e10f
#define B26_LO 0.0f
#define B26_HI 2e10f
#define B66_LO 5e9f
#define B66_HI 3e10f

static __device__ __constant__ float kScale  = (float)(DT_ * DT_ / (H_ * H_) / RHO_);
static __device__ __constant__ float kSrcScl = (float)(DT_ * DT_ / RHO_);

__device__ __forceinline__ float clipf(float v, float lo, float hi) {
    return fminf(fmaxf(v, lo), hi);
}
__device__ __forceinline__ float2 f2(float x, float y) { return make_float2(x, y); }

// ws float layout:
// [0..7NPT): coeff planes A11,A22,A12p66,A16,A26,A66,GS (pre-scaled)
// [7NPT..9NPT):  U0 (float2[NPT])
// [9NPT..11NPT): U1 (float2[NPT])
// [11NPT..):     flags (int[GBX*GBY*FLAG_STRIDE])

__global__ __launch_bounds__(256)
void setup_kernel(const float* __restrict__ lc11, const float* __restrict__ lc12,
                  const float* __restrict__ lc16, const float* __restrict__ lc22,
                  const float* __restrict__ lc26, const float* __restrict__ lc66,
                  const float* __restrict__ gauss, float* __restrict__ ws) {
    int i = blockIdx.x * blockDim.x + threadIdx.x;
    if (i >= NPT) return;
    float C11 = clipf(expf(lc11[i]), B11_LO, B11_HI);
    float C12 = clipf(expf(lc12[i]), B12_LO, B12_HI);
    float C16 = clipf(expf(lc16[i]), B16_LO, B16_HI);
    float C22 = clipf(expf(lc22[i]), B22_LO, B22_HI);
    float C26 = clipf(expf(lc26[i]), B26_LO, B26_HI);
    float C66 = clipf(expf(lc66[i]), B66_LO, B66_HI);
    float s = kScale;
    ws[0 * NPT + i] = C11 * s;
    ws[1 * NPT + i] = C22 * s;
    ws[2 * NPT + i] = (C12 + C66) * s;
    ws[3 * NPT + i] = C16 * s;
    ws[4 * NPT + i] = C26 * s;
    ws[5 * NPT + i] = C66 * s;
    ws[6 * NPT + i] = gauss[i] * kSrcScl;
    // zero U0 (= u^0); U1 is fully written before first read
    float2* u0 = (float2*)(ws + 7 * (size_t)NPT);
    u0[i] = f2(0.0f, 0.0f);
    // init flags to 0 (= "u^0 available")
    if (i < GBX * GBY * FLAG_STRIDE) {
        int* flags = (int*)(ws + 11 * (size_t)NPT);
        flags[i] = 0;
    }
}

__global__ __launch_bounds__(NTHR, 1)
void persist_kernel(float* __restrict__ ws, const float* __restrict__ sig,
                    float* __restrict__ out) {
    // dummy LDS: cap occupancy at 2 blocks/CU so 256 blocks are always
    // co-resident (capacity 2*nCU >= 256 even with heavy CU harvesting)
    __shared__ int lds_pad[16384];
    ((volatile int*)lds_pad)[threadIdx.x & 63] = 0;

    float2* u0 = (float2*)(ws + 7 * (size_t)NPT);
    float2* u1 = (float2*)(ws + 9 * (size_t)NPT);
    int* flags  = (int*)(ws + 11 * (size_t)NPT);

    const int tid = threadIdx.x;
    const int rl = tid >> 4;           // 0..11
    const int cl = (tid & 15) * 3;     // 0..45
    const int gr = blockIdx.y * TR + rl;
    const int gc = blockIdx.x * TC + cl;
    const int gbase = gr * NYg + gc;

    // per-thread persistent state: 3 points in a row
    float2 cur[3], old_[3];
    float a11[3], a22[3], a12p66[3], a16[3], a26[3], a66[3], gs[3];
#pragma unroll
    for (int j = 0; j < 3; ++j) {
        int g = gbase + j;
        cur[j]  = f2(0.0f, 0.0f);
        old_[j] = f2(0.0f, 0.0f);
        a11[j]    = ws[0 * NPT + g];
        a22[j]    = ws[1 * NPT + g];
        a12p66[j] = ws[2 * NPT + g];
        a16[j]    = ws[3 * NPT + g];
        a26[j]    = ws[4 * NPT + g];
        a66[j]    = ws[5 * NPT + g];
        gs[j]     = ws[6 * NPT + g];
    }

    // neighbor flag index for poller lanes 0..7
    int nbFlag = -1;
    if (tid < 8) {
        const int dr[8] = {-1, -1, -1,  0, 0,  1, 1, 1};
        const int dc[8] = {-1,  0,  1, -1, 1, -1, 0, 1};
        int nby = (int)blockIdx.y + dr[tid];
        int nbx = (int)blockIdx.x + dc[tid];
        if (nbx >= 0 && nbx < GBX && nby >= 0 && nby < GBY)
            nbFlag = (nby * GBX + nbx) * FLAG_STRIDE;
    }
    const int myFlag = ((int)blockIdx.y * GBX + (int)blockIdx.x) * FLAG_STRIDE;

    // boundary guards (zero-pad domain boundary)
    const bool topOk   = (gr > 0);
    const bool botOk   = (gr < NXg - 1);
    const bool leftOk  = (gc > 0);
    const bool rightOk = (gc + 3 < NYg);

    const int rowUp = gbase - NYg;
    const int rowDn = gbase + NYg;

#pragma unroll 1
    for (int i = 1; i <= NSTEPS; ++i) {
        // ---- wait for 8 neighbors to have published step i-1 ----
        if (i > 1 && nbFlag >= 0) {
            long spin = 0;
            while (__hip_atomic_load(&flags[nbFlag], __ATOMIC_ACQUIRE,
                                     __HIP_MEMORY_SCOPE_AGENT) < i - 1) {
                __builtin_amdgcn_s_sleep(1);
                if (++spin > 50000000L) break;   // hang guard
            }
        }
        __syncthreads();

        const float2* __restrict__ rb = (i & 1) ? u0 : u1;  // u^{i-1}
        float2* __restrict__ wb       = (i & 1) ? u1 : u0;  // write u^i
        const float sig_t = sig[i - 1];

        // ---- load 14x? window: top row 5, bottom row 5, mid left/right ----
        float2 T[5], B[5], M[5];
        T[0] = (topOk && leftOk)  ? rb[rowUp - 1] : f2(0, 0);
        T[4] = (topOk && rightOk) ? rb[rowUp + 3] : f2(0, 0);
        B[0] = (botOk && leftOk)  ? rb[rowDn - 1] : f2(0, 0);
        B[4] = (botOk && rightOk) ? rb[rowDn + 3] : f2(0, 0);
#pragma unroll
        for (int j = 0; j < 3; ++j) {
            T[j + 1] = topOk ? rb[rowUp + j] : f2(0, 0);
            B[j + 1] = botOk ? rb[rowDn + j] : f2(0, 0);
        }
        M[0] = leftOk  ? rb[gbase - 1] : f2(0, 0);
        M[4] = rightOk ? rb[gbase + 3] : f2(0, 0);
        M[1] = cur[0]; M[2] = cur[1]; M[3] = cur[2];

        // ---- update 3 points ----
#pragma unroll
        for (int j = 0; j < 3; ++j) {
            float2 c = M[j + 1];
            float sxx_x = T[j + 1].x + B[j + 1].x - 2.0f * c.x;
            float sxx_y = T[j + 1].y + B[j + 1].y - 2.0f * c.y;
            float syy_x = M[j].x + M[j + 2].x - 2.0f * c.x;
            float syy_y = M[j].y + M[j + 2].y - 2.0f * c.y;
            float sxy_x = 0.25f * (T[j].x - T[j + 2].x - B[j].x + B[j + 2].x);
            float sxy_y = 0.25f * (T[j].y - T[j + 2].y - B[j].y + B[j + 2].y);

            float lux = fmaf(a11[j], sxx_x,
                        fmaf(a66[j], syy_x,
                        fmaf(a12p66[j], sxy_y,
                        fmaf(a16[j], fmaf(2.0f, sxy_x, sxx_y),
                             a26[j] * syy_y))));
            float luy = fmaf(a66[j], sxx_y,
                        fmaf(a22[j], syy_y,
                        fmaf(a12p66[j], sxy_x,
                        fmaf(a16[j], sxx_x,
                             a26[j] * fmaf(2.0f, sxy_y, syy_x)))));

            float nx = fmaf(2.0f, c.x, lux) - old_[j].x;
            float ny = fmaf(2.0f, c.y, fmaf(sig_t, gs[j], luy)) - old_[j].y;
            old_[j] = c;
            cur[j] = f2(nx, ny);
            wb[gbase + j] = cur[j];
        }

        // ---- frame output: u^i == ref scan index i-1; (i-1)%4==3 <=> i%4==0
        if ((i & 3) == 0) {
            int f = (i >> 2) - 1;
            float* oux = out + (size_t)f * NPT;
            float* ouy = out + (size_t)(NFRAMES + f) * NPT;
#pragma unroll
            for (int j = 0; j < 3; ++j) {
                oux[gbase + j] = cur[j].x;
                ouy[gbase + j] = cur[j].y;
            }
        }

        // ---- publish: all block stores drained at barrier, then fence+flag
        __syncthreads();
        if (tid == 0) {
            __threadfence();   // agent-scope release (L2 writeback)
            __hip_atomic_store(&flags[myFlag], i, __ATOMIC_RELEASE,
                               __HIP_MEMORY_SCOPE_AGENT);
        }
    }
}

extern "C" void kernel_launch(void* const* d_in, const int* in_sizes, int n_in,
                              void* d_out, int out_size, void* d_ws, size_t ws_size,
                              hipStream_t stream) {
    const float* lc11  = (const float*)d_in[0];
    const float* lc12  = (const float*)d_in[1];
    const float* lc16  = (const float*)d_in[2];
    const float* lc22  = (const float*)d_in[3];
    const float* lc26  = (const float*)d_in[4];
    const float* lc66  = (const float*)d_in[5];
    const float* gauss = (const float*)d_in[6];
    const float* sig   = (const float*)d_in[7];

    float* ws  = (float*)d_ws;
    float* out = (float*)d_out;

    setup_kernel<<<(NPT + 255) / 256, 256, 0, stream>>>(lc11, lc12, lc16, lc22,
                                                        lc26, lc66, gauss, ws);

    dim3 grid(GBX, GBY);  // 8 x 32 = 256 blocks
    persist_kernel<<<grid, NTHR, 0, stream>>>(ws, sig, out);
}

// Round 6
// 536.903 us; speedup vs baseline: 7.7063x; 7.7063x over previous
//
#include <hip/hip_runtime.h>

// Spatially varying anisotropic 2D elastic wave sim, 384x384, 192 steps.
// Round 5: SINGLE-WAVE blocks, barrier-free time tiling.
//  - block = 64 threads = ONE wave; LDS exchange needs NO __syncthreads
//    (wave64 lockstep; lgkmcnt ordering is automatic) -> no phase-lock
//  - 3x3 pts/thread, 24x24 staging, owned 12x12, halo 6 -> K=6 steps/launch
//  - 1024 blocks = 4 single-wave blocks/CU (one per SIMD); independent waves
//    overlap VALU and LDS naturally
//  - 32 fused launches + 1 setup; launch boundary is the grid sync
//    (R4 lesson: per-step cross-XCD coherence costs ~10x a launch)

#define NXg 384
#define NYg 384
#define NPT (NXg * NYg)
#define NFRAMES 48

#define OWN 12
#define HALO 6
#define TS 24         // staging edge = OWN + 2*HALO
#define KS 6          // fused steps per launch
#define NLAUNCH 32    // 192 / 6

#define H_   1e-4
#define DT_  5e-9
#define RHO_ 1610.0

#define B11_LO 5e10f
#define B11_HI 2.5e11f
#define B22_LO 5e9f
#define B22_HI 5e10f
#define B12_LO 5e9f
#define B12_HI 5e10f
#define B16_LO 0.0f
#define B16_HI 6e10f
#define B26_LO 0.0f
#define B26_HI 2e10f
#define B66_LO 5e9f
#define B66_HI 3e10f

static __device__ __constant__ float kScale  = (float)(DT_ * DT_ / (H_ * H_) / RHO_);
static __device__ __constant__ float kSrcScl = (float)(DT_ * DT_ / RHO_);

__device__ __forceinline__ float clipf(float v, float lo, float hi) {
    return fminf(fmaxf(v, lo), hi);
}
__device__ __forceinline__ float2 f2(float x, float y) { return make_float2(x, y); }
__device__ __forceinline__ float2 fadd2(float2 a, float2 b) { return f2(a.x + b.x, a.y + b.y); }
__device__ __forceinline__ float2 fsub2(float2 a, float2 b) { return f2(a.x - b.x, a.y - b.y); }
__device__ __forceinline__ float2 fscl2(float s, float2 a) { return f2(s * a.x, s * a.y); }
__device__ __forceinline__ float2 ffma2(float s, float2 a, float2 b) {
    return f2(fmaf(s, a.x, b.x), fmaf(s, a.y, b.y));
}

// ws float layout:
// [0..7NPT): coeff planes A11,A22,A12p66,A16,A26,A66,GS (pre-scaled)
// [7NPT..9NPT):   set0 cur (float2[NPT])
// [9NPT..11NPT):  set0 old
// [11NPT..13NPT): set1 cur
// [13NPT..15NPT): set1 old

__global__ __launch_bounds__(256)
void setup_kernel(const float* __restrict__ lc11, const float* __restrict__ lc12,
                  const float* __restrict__ lc16, const float* __restrict__ lc22,
                  const float* __restrict__ lc26, const float* __restrict__ lc66,
                  const float* __restrict__ gauss, float* __restrict__ ws) {
    int i = blockIdx.x * blockDim.x + threadIdx.x;
    if (i >= NPT) return;
    float C11 = clipf(expf(lc11[i]), B11_LO, B11_HI);
    float C12 = clipf(expf(lc12[i]), B12_LO, B12_HI);
    float C16 = clipf(expf(lc16[i]), B16_LO, B16_HI);
    float C22 = clipf(expf(lc22[i]), B22_LO, B22_HI);
    float C26 = clipf(expf(lc26[i]), B26_LO, B26_HI);
    float C66 = clipf(expf(lc66[i]), B66_LO, B66_HI);
    float s = kScale;
    ws[0 * NPT + i] = C11 * s;
    ws[1 * NPT + i] = C22 * s;
    ws[2 * NPT + i] = (C12 + C66) * s;
    ws[3 * NPT + i] = C16 * s;
    ws[4 * NPT + i] = C26 * s;
    ws[5 * NPT + i] = C66 * s;
    ws[6 * NPT + i] = gauss[i] * kSrcScl;
    float2* c0p = (float2*)(ws + 7 * (size_t)NPT);
    float2* o0p = (float2*)(ws + 9 * (size_t)NPT);
    c0p[i] = f2(0.0f, 0.0f);
    o0p[i] = f2(0.0f, 0.0f);
}

__global__ __launch_bounds__(64, 1)
void wave_kernel(const float* __restrict__ ws, const float* __restrict__ sig,
                 const float2* __restrict__ inCur, const float2* __restrict__ inOld,
                 float2* __restrict__ outCur, float2* __restrict__ outOld,
                 float* __restrict__ out, int L) {
    __shared__ float2 sb[2][TS][TS + 2];

    const int tid = threadIdx.x;      // one wave
    const int tx = tid >> 3;          // 0..7 row group
    const int ty = tid & 7;           // 0..7 col group
    const int r0 = 3 * tx;
    const int c0 = 3 * ty;
    const int gx0 = blockIdx.y * OWN - HALO;
    const int gy0 = blockIdx.x * OWN - HALO;

    float2 cur[9], old_[9];
    float a11[9], a22[9], a12p66[9], a16[9], a26[9], a66[9], gs[9];
    int gidx[9];

#pragma unroll
    for (int i = 0; i < 3; ++i) {
#pragma unroll
        for (int j = 0; j < 3; ++j) {
            int p = i * 3 + j;
            int gx = gx0 + r0 + i;
            int gy = gy0 + c0 + j;
            bool d = (unsigned)gx < (unsigned)NXg && (unsigned)gy < (unsigned)NYg;
            int g = d ? gx * NYg + gy : 0;
            gidx[p] = g;
            cur[p]  = d ? inCur[g] : f2(0.0f, 0.0f);
            old_[p] = d ? inOld[g] : f2(0.0f, 0.0f);
            // out-of-domain -> zero coeffs => point stays exactly 0
            a11[p]    = d ? ws[0 * NPT + g] : 0.0f;
            a22[p]    = d ? ws[1 * NPT + g] : 0.0f;
            a12p66[p] = d ? ws[2 * NPT + g] : 0.0f;
            a16[p]    = d ? ws[3 * NPT + g] : 0.0f;
            a26[p]    = d ? ws[4 * NPT + g] : 0.0f;
            a66[p]    = d ? ws[5 * NPT + g] : 0.0f;
            gs[p]     = d ? ws[6 * NPT + g] : 0.0f;
        }
    }

    // clamped halo coords (rim garbage is finite and never read by valid cells)
    const int rm = (r0 > 0) ? r0 - 1 : 0;
    const int rp = (r0 + 3 < TS) ? r0 + 3 : TS - 1;
    const int cm = (c0 > 0) ? c0 - 1 : 0;
    const int cp = (c0 + 3 < TS) ? c0 + 3 : TS - 1;

    const bool owned = (tx >= 2) && (tx < 6) && (ty >= 2) && (ty < 6);
    const int t0 = L * KS;

    // publish initial values (no barrier: single wave, lgkmcnt orders LDS)
#pragma unroll
    for (int i = 0; i < 3; ++i)
#pragma unroll
        for (int j = 0; j < 3; ++j)
            sb[0][r0 + i][c0 + j] = cur[i * 3 + j];
    __builtin_amdgcn_wave_barrier();   // scheduling fence only (no-op inst)

#pragma unroll 1
    for (int s = 1; s <= KS; ++s) {
        const float2 (*rb)[TS + 2] = sb[(s - 1) & 1];
        float2 (*wb)[TS + 2] = sb[s & 1];
        const float sig_t = sig[t0 + s - 1];

        // assemble 5x5 float2 window: own 3x3 from regs + 16 halo reads
        float2 v[5][5];
#pragma unroll
        for (int i = 0; i < 3; ++i)
#pragma unroll
            for (int j = 0; j < 3; ++j)
                v[i + 1][j + 1] = cur[i * 3 + j];
        v[0][0] = rb[rm][cm];  v[0][4] = rb[rm][cp];
        v[4][0] = rb[rp][cm];  v[4][4] = rb[rp][cp];
#pragma unroll
        for (int j = 0; j < 3; ++j) {
            v[0][j + 1] = rb[rm][c0 + j];
            v[4][j + 1] = rb[rp][c0 + j];
            v[j + 1][0] = rb[r0 + j][cm];
            v[j + 1][4] = rb[r0 + j][cp];
        }

        // horizontal differences shared across the 9 points' cross-derivs
        float2 dh[5][3];
#pragma unroll
        for (int i = 0; i < 5; ++i)
#pragma unroll
            for (int j = 0; j < 3; ++j)
                dh[i][j] = fsub2(v[i][j + 2], v[i][j]);

#pragma unroll
        for (int i = 0; i < 3; ++i)
#pragma unroll
            for (int j = 0; j < 3; ++j) {
                int p = i * 3 + j;
                float2 c = v[i + 1][j + 1];
                float2 sxx = ffma2(-2.0f, c, fadd2(v[i][j + 1], v[i + 2][j + 1]));
                float2 syy = ffma2(-2.0f, c, fadd2(v[i + 1][j], v[i + 1][j + 2]));
                float2 sxy = fscl2(0.25f, fsub2(dh[i + 2][j], dh[i][j]));

                float lux = fmaf(a11[p], sxx.x,
                            fmaf(a66[p], syy.x,
                            fmaf(a12p66[p], sxy.y,
                            fmaf(a16[p], fmaf(2.0f, sxy.x, sxx.y),
                                 a26[p] * syy.y))));
                float luy = fmaf(a66[p], sxx.y,
                            fmaf(a22[p], syy.y,
                            fmaf(a12p66[p], sxy.x,
                            fmaf(a16[p], sxx.x,
                                 a26[p] * fmaf(2.0f, sxy.y, syy.x)))));

                float nx = fmaf(2.0f, c.x, lux) - old_[p].x;
                float ny = fmaf(2.0f, c.y, fmaf(sig_t, gs[p], luy)) - old_[p].y;
                old_[p] = c;
                cur[p] = f2(nx, ny);
            }

        // frame output: u^{t0+s}; frame when (t0+s)%4==0, f=(t0+s)/4-1
        const int t0s = t0 + s;
        if ((t0s & 3) == 0 && owned) {
            int f = (t0s >> 2) - 1;
            float* oux = out + (size_t)f * NPT;
            float* ouy = out + (size_t)(NFRAMES + f) * NPT;
#pragma unroll
            for (int p = 0; p < 9; ++p) {
                oux[gidx[p]] = cur[p].x;
                ouy[gidx[p]] = cur[p].y;
            }
        }

        // publish new values into other buffer (no barrier needed)
#pragma unroll
        for (int i = 0; i < 3; ++i)
#pragma unroll
            for (int j = 0; j < 3; ++j)
                wb[r0 + i][c0 + j] = cur[i * 3 + j];
        __builtin_amdgcn_wave_barrier();
    }

    if (owned) {
#pragma unroll
        for (int p = 0; p < 9; ++p) {
            int g = gidx[p];
            outCur[g] = cur[p];
            outOld[g] = old_[p];
        }
    }
}

extern "C" void kernel_launch(void* const* d_in, const int* in_sizes, int n_in,
                              void* d_out, int out_size, void* d_ws, size_t ws_size,
                              hipStream_t stream) {
    const float* lc11  = (const float*)d_in[0];
    const float* lc12  = (const float*)d_in[1];
    const float* lc16  = (const float*)d_in[2];
    const float* lc22  = (const float*)d_in[3];
    const float* lc26  = (const float*)d_in[4];
    const float* lc66  = (const float*)d_in[5];
    const float* gauss = (const float*)d_in[6];
    const float* sig   = (const float*)d_in[7];

    float* ws  = (float*)d_ws;
    float* out = (float*)d_out;

    setup_kernel<<<(NPT + 255) / 256, 256, 0, stream>>>(lc11, lc12, lc16, lc22,
                                                        lc26, lc66, gauss, ws);

    float2* set0c = (float2*)(ws + 7 * (size_t)NPT);
    float2* set0o = (float2*)(ws + 9 * (size_t)NPT);
    float2* set1c = (float2*)(ws + 11 * (size_t)NPT);
    float2* set1o = (float2*)(ws + 13 * (size_t)NPT);

    dim3 grid(NXg / OWN, NYg / OWN);  // 32 x 32 = 1024 single-wave blocks
    for (int L = 0; L < NLAUNCH; ++L) {
        float2* ic = (L & 1) ? set1c : set0c;
        float2* io = (L & 1) ? set1o : set0o;
        float2* oc = (L & 1) ? set0c : set1c;
        float2* oo = (L & 1) ? set0o : set1o;
        wave_kernel<<<grid, 64, 0, stream>>>(ws, sig, ic, io, oc, oo, out, L);
    }
}

// Round 7
// 363.564 us; speedup vs baseline: 11.3805x; 1.4768x over previous
//
#include <hip/hip_runtime.h>

// Spatially varying anisotropic 2D elastic wave sim, 384x384, 192 steps.
// Round 6: R2 geometry (256 blocks = 1/CU, 256 thr, 48x48 staging, K=12,
// 16 launches) with the two biggest per-step costs cut:
//  - LDS exchange packed: (ux,uy) as one b64 element -> 25 LDS ops/thread/step
//    (was 50 scalar b32 in R2)
//  - stencil assembly on clang ext_vector float2 + __builtin_elementwise_fma
//    -> v_pk_add/fma_f32 (VOP3P), ~40% VALU cut; anisotropic cross-coupling
//    stays scalar fmaf (identical rounding to the R2/R3 passing kernels)

typedef float v2f __attribute__((ext_vector_type(2)));

#define NXg 384
#define NYg 384
#define NPT (NXg * NYg)
#define NFRAMES 48

#define OWN 24
#define HALO 12
#define TS 48
#define KSTEPS 12
#define NLAUNCH 16

#define H_   1e-4
#define DT_  5e-9
#define RHO_ 1610.0

#define B11_LO 5e10f
#define B11_HI 2.5e11f
#define B22_LO 5e9f
#define B22_HI 5e10f
#define B12_LO 5e9f
#define B12_HI 5e10f
#define B16_LO 0.0f
#define B16_HI 6e10f
#define B26_LO 0.0f
#define B26_HI 2e10f
#define B66_LO 5e9f
#define B66_HI 3e10f

static __device__ __constant__ float kScale  = (float)(DT_ * DT_ / (H_ * H_) / RHO_);
static __device__ __constant__ float kSrcScl = (float)(DT_ * DT_ / RHO_);

__device__ __forceinline__ float clipf(float v, float lo, float hi) {
    return fminf(fmaxf(v, lo), hi);
}
__device__ __forceinline__ v2f vfma(v2f a, v2f b, v2f c) {
    return __builtin_elementwise_fma(a, b, c);
}
__device__ __forceinline__ v2f vbc(float s) { v2f r; r[0] = s; r[1] = s; return r; }

// ws float layout:
// [0..7NPT): coeff planes A11,A22,A12p66,A16,A26,A66,GS (pre-scaled)
// [7NPT..11NPT):  state set0 (cur v2f[NPT], old v2f[NPT])
// [11NPT..15NPT): state set1

__global__ __launch_bounds__(256)
void setup_kernel(const float* __restrict__ lc11, const float* __restrict__ lc12,
                  const float* __restrict__ lc16, const float* __restrict__ lc22,
                  const float* __restrict__ lc26, const float* __restrict__ lc66,
                  const float* __restrict__ gauss, float* __restrict__ ws) {
    int i = blockIdx.x * blockDim.x + threadIdx.x;
    if (i >= NPT) return;
    float C11 = clipf(expf(lc11[i]), B11_LO, B11_HI);
    float C12 = clipf(expf(lc12[i]), B12_LO, B12_HI);
    float C16 = clipf(expf(lc16[i]), B16_LO, B16_HI);
    float C22 = clipf(expf(lc22[i]), B22_LO, B22_HI);
    float C26 = clipf(expf(lc26[i]), B26_LO, B26_HI);
    float C66 = clipf(expf(lc66[i]), B66_LO, B66_HI);
    float s = kScale;
    ws[0 * NPT + i] = C11 * s;
    ws[1 * NPT + i] = C22 * s;
    ws[2 * NPT + i] = (C12 + C66) * s;
    ws[3 * NPT + i] = C16 * s;
    ws[4 * NPT + i] = C26 * s;
    ws[5 * NPT + i] = C66 * s;
    ws[6 * NPT + i] = gauss[i] * kSrcScl;
    v2f* c0 = (v2f*)(ws + 7 * (size_t)NPT);
    v2f* o0 = c0 + NPT;
    c0[i] = vbc(0.0f);
    o0[i] = vbc(0.0f);
}

__global__ __launch_bounds__(256, 1)
void fused_kernel(const float* __restrict__ ws, const float* __restrict__ sig,
                  const v2f* __restrict__ inCur, const v2f* __restrict__ inOld,
                  v2f* __restrict__ outCur, v2f* __restrict__ outOld,
                  float* __restrict__ out, int L) {
    __shared__ v2f sb[2][TS][TS + 1];

    const int tid = threadIdx.x;
    const int tx = tid >> 4;
    const int ty = tid & 15;
    const int r0 = 3 * tx;
    const int c0 = 3 * ty;
    const int gx0 = blockIdx.y * OWN - HALO;
    const int gy0 = blockIdx.x * OWN - HALO;

    v2f cur[9], old_[9];
    float a11[9], a22[9], a12p66[9], a16[9], a26[9], a66[9], gs[9];
    int gidx[9];

#pragma unroll
    for (int i = 0; i < 3; ++i) {
#pragma unroll
        for (int j = 0; j < 3; ++j) {
            int p = i * 3 + j;
            int gx = gx0 + r0 + i;
            int gy = gy0 + c0 + j;
            bool d = (unsigned)gx < (unsigned)NXg && (unsigned)gy < (unsigned)NYg;
            int g = d ? gx * NYg + gy : 0;
            gidx[p] = g;
            cur[p]  = d ? inCur[g] : vbc(0.0f);
            old_[p] = d ? inOld[g] : vbc(0.0f);
            // out-of-domain -> zero coeffs => point stays exactly 0
            a11[p]    = d ? ws[0 * NPT + g] : 0.0f;
            a22[p]    = d ? ws[1 * NPT + g] : 0.0f;
            a12p66[p] = d ? ws[2 * NPT + g] : 0.0f;
            a16[p]    = d ? ws[3 * NPT + g] : 0.0f;
            a26[p]    = d ? ws[4 * NPT + g] : 0.0f;
            a66[p]    = d ? ws[5 * NPT + g] : 0.0f;
            gs[p]     = d ? ws[6 * NPT + g] : 0.0f;
        }
    }

    // clamped halo coords (trapezoid garbage-tolerance at staging rim)
    const int rm = (r0 > 0) ? r0 - 1 : 0;
    const int rp = (r0 + 3 < TS) ? r0 + 3 : TS - 1;
    const int cm = (c0 > 0) ? c0 - 1 : 0;
    const int cp = (c0 + 3 < TS) ? c0 + 3 : TS - 1;

    const bool owned = (tx >= 4) && (tx < 12) && (ty >= 4) && (ty < 12);
    const int t0 = L * KSTEPS;

    // publish initial values into buffer 0
#pragma unroll
    for (int i = 0; i < 3; ++i)
#pragma unroll
        for (int j = 0; j < 3; ++j)
            sb[0][r0 + i][c0 + j] = cur[i * 3 + j];
    __syncthreads();

#pragma unroll 1
    for (int s = 1; s <= KSTEPS; ++s) {
        const v2f (*rb)[TS + 1] = sb[(s - 1) & 1];
        v2f (*wb)[TS + 1] = sb[s & 1];
        const float sig_t = sig[t0 + s - 1];

        // assemble 5x5 v2f window: own 3x3 from regs + 16 halo b64 reads
        v2f v[5][5];
#pragma unroll
        for (int i = 0; i < 3; ++i)
#pragma unroll
            for (int j = 0; j < 3; ++j)
                v[i + 1][j + 1] = cur[i * 3 + j];
        v[0][0] = rb[rm][cm];  v[0][4] = rb[rm][cp];
        v[4][0] = rb[rp][cm];  v[4][4] = rb[rp][cp];
#pragma unroll
        for (int j = 0; j < 3; ++j) {
            v[0][j + 1] = rb[rm][c0 + j];
            v[4][j + 1] = rb[rp][c0 + j];
            v[j + 1][0] = rb[r0 + j][cm];
            v[j + 1][4] = rb[r0 + j][cp];
        }

        // horizontal differences shared across the 9 points' cross-derivs
        v2f dh[5][3];
#pragma unroll
        for (int i = 0; i < 5; ++i)
#pragma unroll
            for (int j = 0; j < 3; ++j)
                dh[i][j] = v[i][j + 2] - v[i][j];

        const v2f m2 = vbc(-2.0f);
        const v2f qt = vbc(0.25f);
#pragma unroll
        for (int i = 0; i < 3; ++i)
#pragma unroll
            for (int j = 0; j < 3; ++j) {
                int p = i * 3 + j;
                v2f c = v[i + 1][j + 1];
                v2f sxx = vfma(m2, c, v[i][j + 1] + v[i + 2][j + 1]);  // pk
                v2f syy = vfma(m2, c, v[i + 1][j] + v[i + 1][j + 2]);  // pk
                v2f sxy = qt * (dh[i + 2][j] - dh[i][j]);              // pk

                float lux = fmaf(a11[p], sxx[0],
                            fmaf(a66[p], syy[0],
                            fmaf(a12p66[p], sxy[1],
                            fmaf(a16[p], fmaf(2.0f, sxy[0], sxx[1]),
                                 a26[p] * syy[1]))));
                float luy = fmaf(a66[p], sxx[1],
                            fmaf(a22[p], syy[1],
                            fmaf(a12p66[p], sxy[0],
                            fmaf(a16[p], sxx[0],
                                 a26[p] * fmaf(2.0f, sxy[1], syy[0])))));

                float nx = fmaf(2.0f, c[0], lux) - old_[p][0];
                float ny = fmaf(2.0f, c[1], fmaf(sig_t, gs[p], luy)) - old_[p][1];
                old_[p] = c;
                v2f n; n[0] = nx; n[1] = ny;
                cur[p] = n;
            }

        // frame output at global t = t0 + s - 1; t%4==3 <=> s%4==0
        if ((s & 3) == 0 && owned) {
            int f = 3 * L + (s >> 2) - 1;
            float* oux = out + (size_t)f * NPT;
            float* ouy = out + (size_t)(NFRAMES + f) * NPT;
#pragma unroll
            for (int p = 0; p < 9; ++p) {
                oux[gidx[p]] = cur[p][0];
                ouy[gidx[p]] = cur[p][1];
            }
        }

        // publish new values; ONE barrier per step (double buffered)
#pragma unroll
        for (int i = 0; i < 3; ++i)
#pragma unroll
            for (int j = 0; j < 3; ++j)
                wb[r0 + i][c0 + j] = cur[i * 3 + j];
        __syncthreads();
    }

    if (owned) {
#pragma unroll
        for (int p = 0; p < 9; ++p) {
            int g = gidx[p];
            outCur[g] = cur[p];
            outOld[g] = old_[p];
        }
    }
}

extern "C" void kernel_launch(void* const* d_in, const int* in_sizes, int n_in,
                              void* d_out, int out_size, void* d_ws, size_t ws_size,
                              hipStream_t stream) {
    const float* lc11  = (const float*)d_in[0];
    const float* lc12  = (const float*)d_in[1];
    const float* lc16  = (const float*)d_in[2];
    const float* lc22  = (const float*)d_in[3];
    const float* lc26  = (const float*)d_in[4];
    const float* lc66  = (const float*)d_in[5];
    const float* gauss = (const float*)d_in[6];
    const float* sig   = (const float*)d_in[7];

    float* ws  = (float*)d_ws;
    float* out = (float*)d_out;

    setup_kernel<<<(NPT + 255) / 256, 256, 0, stream>>>(lc11, lc12, lc16, lc22,
                                                        lc26, lc66, gauss, ws);

    v2f* set0c = (v2f*)(ws + 7 * (size_t)NPT);
    v2f* set0o = set0c + NPT;
    v2f* set1c = (v2f*)(ws + 11 * (size_t)NPT);
    v2f* set1o = set1c + NPT;

    dim3 grid(NXg / OWN, NYg / OWN);  // 16x16 = 256 blocks, 1 per CU
    for (int L = 0; L < NLAUNCH; ++L) {
        v2f* ic = (L & 1) ? set1c : set0c;
        v2f* io = (L & 1) ? set1o : set0o;
        v2f* oc = (L & 1) ? set0c : set1c;
        v2f* oo = (L & 1) ? set0o : set1o;
        fused_kernel<<<grid, 256, 0, stream>>>(ws, sig, ic, io, oc, oo, out, L);
    }
}